// Round 1
// baseline (801.631 us; speedup 1.0000x reference)
//
#include <hip/hip_runtime.h>
#include <hip/hip_bf16.h>
#include <math.h>

typedef __bf16 bf16x8 __attribute__((ext_vector_type(8)));
typedef __bf16 bf16x4 __attribute__((ext_vector_type(4)));
typedef float  f32x4  __attribute__((ext_vector_type(4)));

#define S_LEN 2048
#define NB    8
#define NH    16
#define NP    8
#define DIM   1024

__device__ __forceinline__ void gld16(const void* g, void* l) {
  __builtin_amdgcn_global_load_lds(
      (__attribute__((address_space(1))) void*)g,
      (__attribute__((address_space(3))) void*)l, 16, 0, 0);
}

// ---------------- small prep kernels ----------------

__global__ void k_cast_bf16(const float* __restrict__ src, __bf16* __restrict__ dst, int n4) {
  int i = blockIdx.x * 256 + threadIdx.x;
  if (i >= n4) return;
  float4 v = reinterpret_cast<const float4*>(src)[i];
  bf16x4 o;
  o.x = (__bf16)v.x; o.y = (__bf16)v.y; o.z = (__bf16)v.z; o.w = (__bf16)v.w;
  reinterpret_cast<bf16x4*>(dst)[i] = o;
}

// dst[n*Kdim + k] = (bf16) W[k*Ndim + n]   (transpose + cast)
__global__ void k_pack_wt(const float* __restrict__ W, __bf16* __restrict__ dst, int Kdim, int Ndim) {
  int idx = blockIdx.x * 256 + threadIdx.x;
  int n = idx / Kdim, kk = idx - n * Kdim;
  dst[idx] = (__bf16)W[(size_t)kk * Ndim + n];
}

__global__ void k_ebias(const float* __restrict__ bq, const float* __restrict__ bk,
                        const float* __restrict__ bv, float* __restrict__ ebias) {
  int i = blockIdx.x * 256 + threadIdx.x;
  if (i >= 3072) return;
  const float* src = (i < 1024) ? bq : (i < 2048) ? bk : bv;
  ebias[i] = src[i & 1023];
}

// wc_t[d] = sum_f Wc[f]*Wt[1024+f][d]; ebt[j][d] = sum_f Eb[j,f]*Wt[1280+f][d];
// biasp[d] = bt[d] + sum_f bc[f]*Wt[1024+f][d]
__global__ void k_precompute(const float* __restrict__ Wc, const float* __restrict__ bc,
                             const float* __restrict__ Eb, const float* __restrict__ Wt,
                             const float* __restrict__ bt,
                             float* __restrict__ wc_t, float* __restrict__ ebt,
                             float* __restrict__ biasp) {
  int d = blockIdx.x * 256 + threadIdx.x;
  if (d >= 1024) return;
  float accW = 0.f, accB = 0.f;
  for (int f = 0; f < 256; ++f) {
    float wt2 = Wt[(size_t)(1024 + f) * 1024 + d];
    accW += Wc[f] * wt2;
    accB += bc[f] * wt2;
  }
  wc_t[d] = accW;
  biasp[d] = bt[d] + accB;
  for (int j = 0; j < 9; ++j) {
    float a = 0.f;
    for (int f = 0; f < 256; ++f)
      a += Eb[j * 256 + f] * Wt[(size_t)(1280 + f) * 1024 + d];
    ebt[j * 1024 + d] = a;
  }
}

__global__ void k_rowfeat(const float* __restrict__ td, float* __restrict__ dl,
                          int* __restrict__ bucket, int n) {
  int i = blockIdx.x * 256 + threadIdx.x;
  if (i >= n) return;
  float dt = fmaxf(td[i], 0.f);
  dl[i] = log1pf(dt);
  const float B0[8] = {0.f, 0.5f, 1.f, 2.f, 4.f, 8.f, 12.f, 24.f};
  int bk = 0;
#pragma unroll
  for (int j = 0; j < 8; ++j) bk += (B0[j] < dt) ? 1 : 0;
  bucket[i] = bk;
}

__global__ void k_cumsum(const float* __restrict__ td, float* __restrict__ el) {
  __shared__ float part[256];
  __shared__ float pre[256];
  int b = blockIdx.x, t = threadIdx.x;
  const float* x = td + b * S_LEN;
  float* o = el + b * S_LEN;
  float loc[8];
  float run = 0.f;
#pragma unroll
  for (int j = 0; j < 8; ++j) { run += fmaxf(x[t * 8 + j], 0.f); loc[j] = run; }
  part[t] = run;
  __syncthreads();
  if (t == 0) {
    float acc = 0.f;
    for (int i = 0; i < 256; ++i) { pre[i] = acc; acc += part[i]; }
  }
  __syncthreads();
  float base = pre[t];
#pragma unroll
  for (int j = 0; j < 8; ++j) o[t * 8 + j] = base + loc[j];
}

// ---------------- GEMM (m97 structure: 128x128 tile, 4 waves, 16x16x32 bf16) ----------------

struct GP {
  const __bf16* A; const __bf16* Bt;
  int M, N, K;
  __bf16 *qb, *kb, *vb, *ctxb;
  const float *ebias, *biasp, *wc_t, *ebt, *dl;
  const int* bucket;
  float *offa, *psa;
  const float *boff, *bps;
  float* outp; const float* bo;
};

template <int MODE>
__global__ __launch_bounds__(256) void k_gemm(GP pr) {
  __shared__ __bf16 As[128 * 32];
  __shared__ __bf16 Bs[128 * 32];
  const int tid = threadIdx.x;
  const int wave = tid >> 6, lane = tid & 63;
  const int wm = wave >> 1, wn = wave & 1;
  const int nbn = pr.N >> 7;
  const int bm = blockIdx.x / nbn, bn = blockIdx.x - bm * nbn;
  const int m0 = bm << 7, n0 = bn << 7;
  const int K = pr.K;
  const int rA = lane & 15, rG = lane >> 4;

  f32x4 acc[4][4] = {};

  for (int k0 = 0; k0 < K; k0 += 32) {
#pragma unroll
    for (int ch = 0; ch < 2; ++ch) {
      const int fb = ch * 4096 + wave * 1024;      // wave-uniform LDS byte base
      const int e = (fb >> 1) + lane * 8;          // per-lane element index
      const int row = e >> 5, col = e & 31;
      gld16(pr.A  + (size_t)(m0 + row) * K + (k0 + col), (char*)As + fb);
      gld16(pr.Bt + (size_t)(n0 + row) * K + (k0 + col), (char*)Bs + fb);
    }
    __syncthreads();

    bf16x8 af[4], bfv[4];
#pragma unroll
    for (int mt = 0; mt < 4; ++mt)
      af[mt] = *(const bf16x8*)&As[(wm * 64 + mt * 16 + rA) * 32 + rG * 8];
#pragma unroll
    for (int nt = 0; nt < 4; ++nt)
      bfv[nt] = *(const bf16x8*)&Bs[(wn * 64 + nt * 16 + rA) * 32 + rG * 8];
#pragma unroll
    for (int mt = 0; mt < 4; ++mt)
#pragma unroll
      for (int nt = 0; nt < 4; ++nt)
        acc[mt][nt] = __builtin_amdgcn_mfma_f32_16x16x32_bf16(af[mt], bfv[nt], acc[mt][nt], 0, 0, 0);
    __syncthreads();
  }

  // epilogue: C/D layout col = lane&15, row = (lane>>4)*4 + i   [m89-verified]
#pragma unroll
  for (int mt = 0; mt < 4; ++mt) {
#pragma unroll
    for (int nt = 0; nt < 4; ++nt) {
      const int gc = n0 + wn * 64 + nt * 16 + rA;
      const int grb = m0 + wm * 64 + mt * 16 + rG * 4;
#pragma unroll
      for (int i = 0; i < 4; ++i) {
        const int gr = grb + i;
        float val = acc[mt][nt][i];
        if constexpr (MODE == 0) {
          const int seg = gc >> 10, d = gc & 1023;
          const int bb = gr >> 11, ss = gr & 2047;
          if (seg < 3) {
            float v = val + pr.ebias[gc];
            const int hh = d >> 6, dh = d & 63;
            __bf16* dst = (seg == 0) ? pr.qb : (seg == 1) ? pr.kb : pr.vb;
            dst[(((size_t)bb * NH + hh) * S_LEN + ss) * 64 + dh] = (__bf16)v;
          } else {
            float v = val + pr.biasp[d] + pr.dl[gr] * pr.wc_t[d]
                      + pr.ebt[pr.bucket[gr] * 1024 + d];
            pr.ctxb[(size_t)gr * 1024 + d] = (__bf16)v;
          }
        } else if constexpr (MODE == 1) {
          const int bb = gr >> 11, ss = gr & 2047;
          const int half = gc >> 7, j = gc & 127;
          const int hh = j >> 3, pp = j & 7;
          size_t di = (((size_t)bb * NH + hh) * S_LEN + ss) * NP + pp;
          if (half == 0) pr.offa[di] = tanhf(val + pr.boff[j]);
          else           pr.psa[di]  = val + pr.bps[j];
        } else {
          pr.outp[(size_t)gr * 1024 + gc] = val + pr.bo[gc];
        }
      }
    }
  }
}

// ---------------- deformable attention: one wave per (b,h,s) ----------------

__global__ __launch_bounds__(256) void k_attn(
    const __bf16* __restrict__ qb, const __bf16* __restrict__ kb, const __bf16* __restrict__ vb,
    const float* __restrict__ offa, const float* __restrict__ psa,
    const float* __restrict__ elapsed,
    const float* __restrict__ point_bias, const float* __restrict__ tdw,
    const float* __restrict__ tdb,
    __bf16* __restrict__ attn_out) {
  const int wid = blockIdx.x * 4 + (threadIdx.x >> 6);
  const int lane = threadIdx.x & 63;
  const int s = wid & (S_LEN - 1);
  const int h = (wid >> 11) & (NH - 1);
  const int b = wid >> 15;
  const int p = lane >> 3, c = lane & 7;

  // anchors: 2^(p*log2(129)/7) - 1, anchor[0]=0 (double math to match numpy)
  const double step = log2(129.0) / 7.0;
  const float anchor = (p == 0) ? 0.0f : (float)(exp2((double)p * step) - 1.0);

  const size_t bhBase = ((size_t)b * NH + h) * S_LEN;
  const size_t ppos = (bhBase + s) * NP + p;
  const float off = offa[ppos];
  const float psv = psa[ppos];

  float pos = (float)s - anchor + off * 8.0f;
  pos = fminf(fmaxf(pos, 0.0f), (float)s);
  int li = (int)pos; if (li > S_LEN - 1) li = S_LEN - 1;
  const float alpha = pos - (float)li;
  int ri = li + 1; if (ri > S_LEN - 1) ri = S_LEN - 1;

  const bf16x8 qv = *(const bf16x8*)(qb + (bhBase + s) * 64 + c * 8);
  const bf16x8 kl = *(const bf16x8*)(kb + (bhBase + li) * 64 + c * 8);
  const bf16x8 kr = *(const bf16x8*)(kb + (bhBase + ri) * 64 + c * 8);

  float dot = 0.f;
#pragma unroll
  for (int j = 0; j < 8; ++j) {
    float klj = (float)kl[j];
    float kf = klj + alpha * ((float)kr[j] - klj);
    dot += (float)qv[j] * kf;
  }
  dot += __shfl_xor(dot, 1);
  dot += __shfl_xor(dot, 2);
  dot += __shfl_xor(dot, 4);

  const float el_s = elapsed[b * S_LEN + s];
  const float ell = elapsed[b * S_LEN + li];
  const float elr = elapsed[b * S_LEN + ri];
  const float elsamp = ell + alpha * (elr - ell);
  const float rel = log1pf(fmaxf(el_s - elsamp, 0.f));
  const int hp = h * NP + p;
  const float decay = log1pf(expf(tdw[hp]));
  float score = dot * 0.125f + psv + tdb[hp] - decay * rel + point_bias[hp];

  float m = score;
  m = fmaxf(m, __shfl_xor(m, 8));
  m = fmaxf(m, __shfl_xor(m, 16));
  m = fmaxf(m, __shfl_xor(m, 32));
  float e = expf(score - m);
  float dsum = e;
  dsum += __shfl_xor(dsum, 8);
  dsum += __shfl_xor(dsum, 16);
  dsum += __shfl_xor(dsum, 32);
  const float w = e / dsum;

  const bf16x8 vl = *(const bf16x8*)(vb + (bhBase + li) * 64 + c * 8);
  const bf16x8 vr = *(const bf16x8*)(vb + (bhBase + ri) * 64 + c * 8);
  float o[8];
#pragma unroll
  for (int j = 0; j < 8; ++j) {
    float vlj = (float)vl[j];
    float vf = vlj + alpha * ((float)vr[j] - vlj);
    o[j] = w * vf;
  }
#pragma unroll
  for (int j = 0; j < 8; ++j) {
    o[j] += __shfl_xor(o[j], 8);
    o[j] += __shfl_xor(o[j], 16);
    o[j] += __shfl_xor(o[j], 32);
  }
  if (p == 0) {
    bf16x8 ov;
#pragma unroll
    for (int j = 0; j < 8; ++j) ov[j] = (__bf16)o[j];
    *(bf16x8*)(attn_out + ((size_t)b * S_LEN + s) * DIM + h * 64 + c * 8) = ov;
  }
}

// ---------------- host ----------------

extern "C" void kernel_launch(void* const* d_in, const int* in_sizes, int n_in,
                              void* d_out, int out_size, void* d_ws, size_t ws_size,
                              hipStream_t stream) {
  const float* x    = (const float*)d_in[0];
  const float* td   = (const float*)d_in[1];
  const float* Wq   = (const float*)d_in[2];
  const float* bq   = (const float*)d_in[3];
  const float* Wk   = (const float*)d_in[4];
  const float* bk   = (const float*)d_in[5];
  const float* Wv   = (const float*)d_in[6];
  const float* bv   = (const float*)d_in[7];
  const float* Wc   = (const float*)d_in[8];
  const float* bc   = (const float*)d_in[9];
  const float* Eb   = (const float*)d_in[10];
  const float* Wt   = (const float*)d_in[11];
  const float* bt   = (const float*)d_in[12];
  const float* Woff = (const float*)d_in[13];
  const float* boff = (const float*)d_in[14];
  const float* Wps  = (const float*)d_in[15];
  const float* bps  = (const float*)d_in[16];
  const float* Wo   = (const float*)d_in[17];
  const float* bo   = (const float*)d_in[18];
  const float* pb   = (const float*)d_in[19];
  const float* tdw  = (const float*)d_in[20];
  const float* tdb  = (const float*)d_in[21];

  char* w = (char*)d_ws;
  size_t off = 0;
  auto take = [&](size_t n) {
    char* pp = w + off;
    off += (n + 255) & ~(size_t)255;
    return pp;
  };
  __bf16* xb    = (__bf16*)take(33554432);  // x bf16 [16384,1024]; reused as attn_out
  __bf16* wcat  = (__bf16*)take(8388608);   // [4096,1024] B^T of Wq|Wk|Wv|Wt1
  __bf16* w2t   = (__bf16*)take(524288);    // [256,1024] B^T of Woff|Wps
  __bf16* wot   = (__bf16*)take(2097152);   // [1024,1024] B^T of Wo
  __bf16* qb    = (__bf16*)take(33554432);  // [B,H,S,64]
  __bf16* kb    = (__bf16*)take(33554432);
  __bf16* vb    = (__bf16*)take(33554432);
  __bf16* ctxb  = (__bf16*)take(33554432);  // [16384,1024]
  float* offa   = (float*)take(8388608);    // [B,H,S,P]
  float* psa    = (float*)take(8388608);
  float* elap   = (float*)take(65536);
  float* dl     = (float*)take(65536);
  int*   bucket = (int*)take(65536);
  float* wc_t   = (float*)take(4096);
  float* ebt    = (float*)take(36864);
  float* biasp  = (float*)take(4096);
  float* ebias  = (float*)take(12288);
  if (off > ws_size) return;
  __bf16* attn_out = xb;  // alias: xb dead after G1

  k_cast_bf16<<<16384, 256, 0, stream>>>(x, xb, 4194304);
  k_pack_wt<<<4096, 256, 0, stream>>>(Wq, wcat, 1024, 1024);
  k_pack_wt<<<4096, 256, 0, stream>>>(Wk, wcat + 1048576, 1024, 1024);
  k_pack_wt<<<4096, 256, 0, stream>>>(Wv, wcat + 2097152, 1024, 1024);
  k_pack_wt<<<4096, 256, 0, stream>>>(Wt, wcat + 3145728, 1024, 1024);  // rows 0..1023 of Wt
  k_pack_wt<<<512, 256, 0, stream>>>(Woff, w2t, 1024, 128);
  k_pack_wt<<<512, 256, 0, stream>>>(Wps, w2t + 131072, 1024, 128);
  k_pack_wt<<<4096, 256, 0, stream>>>(Wo, wot, 1024, 1024);
  k_ebias<<<12, 256, 0, stream>>>(bq, bk, bv, ebias);
  k_precompute<<<4, 256, 0, stream>>>(Wc, bc, Eb, Wt, bt, wc_t, ebt, biasp);
  k_rowfeat<<<64, 256, 0, stream>>>(td, dl, bucket, 16384);
  k_cumsum<<<8, 256, 0, stream>>>(td, elap);

  GP g1 = {};
  g1.A = xb; g1.Bt = wcat; g1.M = 16384; g1.N = 4096; g1.K = 1024;
  g1.qb = qb; g1.kb = kb; g1.vb = vb; g1.ctxb = ctxb;
  g1.ebias = ebias; g1.biasp = biasp; g1.wc_t = wc_t; g1.ebt = ebt;
  g1.dl = dl; g1.bucket = bucket;
  k_gemm<0><<<128 * 32, 256, 0, stream>>>(g1);

  GP g2 = {};
  g2.A = ctxb; g2.Bt = w2t; g2.M = 16384; g2.N = 256; g2.K = 1024;
  g2.offa = offa; g2.psa = psa; g2.boff = boff; g2.bps = bps;
  k_gemm<1><<<128 * 2, 256, 0, stream>>>(g2);

  k_attn<<<65536, 256, 0, stream>>>(qb, kb, vb, offa, psa, elap, pb, tdw, tdb, attn_out);

  GP g3 = {};
  g3.A = attn_out; g3.Bt = wot; g3.M = 16384; g3.N = 1024; g3.K = 1024;
  g3.outp = (float*)d_out; g3.bo = bo;
  k_gemm<2><<<128 * 8, 256, 0, stream>>>(g3);
}

// Round 2
// 638.277 us; speedup vs baseline: 1.2559x; 1.2559x over previous
//
#include <hip/hip_runtime.h>
#include <hip/hip_bf16.h>
#include <math.h>

typedef __bf16 bf16x8 __attribute__((ext_vector_type(8)));
typedef __bf16 bf16x4 __attribute__((ext_vector_type(4)));
typedef float  f32x4  __attribute__((ext_vector_type(4)));

#define S_LEN 2048
#define NB    8
#define NH    16
#define NP    8
#define DIM   1024

__device__ __forceinline__ void gld16(const void* g, void* l) {
  __builtin_amdgcn_global_load_lds(
      (__attribute__((address_space(1))) void*)g,
      (__attribute__((address_space(3))) void*)l, 16, 0, 0);
}

// ---------------- small prep kernels ----------------

__global__ void k_cast_bf16(const float* __restrict__ src, __bf16* __restrict__ dst, int n4) {
  int i = blockIdx.x * 256 + threadIdx.x;
  if (i >= n4) return;
  float4 v = reinterpret_cast<const float4*>(src)[i];
  bf16x4 o;
  o.x = (__bf16)v.x; o.y = (__bf16)v.y; o.z = (__bf16)v.z; o.w = (__bf16)v.w;
  reinterpret_cast<bf16x4*>(dst)[i] = o;
}

// LDS-tiled transpose: dst[n*K + k] = (bf16) W[k*N + n], K,N multiples of 64
__global__ __launch_bounds__(256) void k_pack_wt2(const float* __restrict__ W,
                                                  __bf16* __restrict__ dst, int K, int N) {
  __shared__ float t[64][65];
  const int ntn = N >> 6;
  const int bk = blockIdx.x / ntn, bn = blockIdx.x - bk * ntn;
  const int tid = threadIdx.x;
  // load 64x64 f32 tile coalesced: thread -> 4 rows x float4
  const int c4 = tid & 15;             // 16 float4 per row
  const int r0 = tid >> 4;             // 16 rows per pass
#pragma unroll
  for (int rp = 0; rp < 4; ++rp) {
    const int row = rp * 16 + r0;
    float4 v = *(const float4*)(W + (size_t)(bk * 64 + row) * N + bn * 64 + c4 * 4);
    t[row][c4 * 4 + 0] = v.x; t[row][c4 * 4 + 1] = v.y;
    t[row][c4 * 4 + 2] = v.z; t[row][c4 * 4 + 3] = v.w;
  }
  __syncthreads();
  // store transposed: thread -> output row n = tid>>2, k-quarter q = tid&3 (16 bf16 = 32B)
  const int n = tid >> 2, q = tid & 3;
  bf16x8 o0, o1;
#pragma unroll
  for (int j = 0; j < 8; ++j) o0[j] = (__bf16)t[q * 16 + j][n];
#pragma unroll
  for (int j = 0; j < 8; ++j) o1[j] = (__bf16)t[q * 16 + 8 + j][n];
  __bf16* dp = dst + (size_t)(bn * 64 + n) * K + bk * 64 + q * 16;
  *(bf16x8*)dp = o0;
  *(bf16x8*)(dp + 8) = o1;
}

__global__ void k_ebias(const float* __restrict__ bq, const float* __restrict__ bk,
                        const float* __restrict__ bv, float* __restrict__ ebias) {
  int i = blockIdx.x * 256 + threadIdx.x;
  if (i >= 3072) return;
  const float* src = (i < 1024) ? bq : (i < 2048) ? bk : bv;
  ebias[i] = src[i & 1023];
}

__global__ void k_precompute(const float* __restrict__ Wc, const float* __restrict__ bc,
                             const float* __restrict__ Eb, const float* __restrict__ Wt,
                             const float* __restrict__ bt,
                             float* __restrict__ wc_t, float* __restrict__ ebt,
                             float* __restrict__ biasp) {
  int d = blockIdx.x * 256 + threadIdx.x;
  if (d >= 1024) return;
  float accW = 0.f, accB = 0.f;
  for (int f = 0; f < 256; ++f) {
    float wt2 = Wt[(size_t)(1024 + f) * 1024 + d];
    accW += Wc[f] * wt2;
    accB += bc[f] * wt2;
  }
  wc_t[d] = accW;
  biasp[d] = bt[d] + accB;
  for (int j = 0; j < 9; ++j) {
    float a = 0.f;
    for (int f = 0; f < 256; ++f)
      a += Eb[j * 256 + f] * Wt[(size_t)(1280 + f) * 1024 + d];
    ebt[j * 1024 + d] = a;
  }
}

__global__ void k_rowfeat(const float* __restrict__ td, float* __restrict__ dl,
                          int* __restrict__ bucket, int n) {
  int i = blockIdx.x * 256 + threadIdx.x;
  if (i >= n) return;
  float dt = fmaxf(td[i], 0.f);
  dl[i] = log1pf(dt);
  const float B0[8] = {0.f, 0.5f, 1.f, 2.f, 4.f, 8.f, 12.f, 24.f};
  int bk = 0;
#pragma unroll
  for (int j = 0; j < 8; ++j) bk += (B0[j] < dt) ? 1 : 0;
  bucket[i] = bk;
}

__global__ void k_cumsum(const float* __restrict__ td, float* __restrict__ el) {
  __shared__ float part[256];
  __shared__ float pre[256];
  int b = blockIdx.x, t = threadIdx.x;
  const float* x = td + b * S_LEN;
  float* o = el + b * S_LEN;
  float loc[8];
  float run = 0.f;
#pragma unroll
  for (int j = 0; j < 8; ++j) { run += fmaxf(x[t * 8 + j], 0.f); loc[j] = run; }
  part[t] = run;
  __syncthreads();
  if (t == 0) {
    float acc = 0.f;
    for (int i = 0; i < 256; ++i) { pre[i] = acc; acc += part[i]; }
  }
  __syncthreads();
  float base = pre[t];
#pragma unroll
  for (int j = 0; j < 8; ++j) o[t * 8 + j] = base + loc[j];
}

// ---------------- GEMM params ----------------

struct GP {
  const __bf16* A; const __bf16* Bt;
  int M, N, K;
  __bf16 *qb, *kb, *vb, *ctxb;
  const float *ebias, *biasp, *wc_t, *ebt, *dl;
  const int* bucket;
  float *offa, *psa;
  const float *boff, *bps;
  float* outp; const float* bo;
};

// ---------------- GEMM 256x256, BK=64, 8 waves, 2-phase dbuf (T3-min) + T2 swizzle ----------------
// Computes C^T fragments (swapped MFMA operands) so each lane owns 4 consecutive
// output columns of one row -> vectorized epilogue stores.

template <int MODE>
__global__ __launch_bounds__(512, 2) void k_gemm2(GP pr) {
  __shared__ __align__(16) __bf16 As[2][256 * 64];
  __shared__ __align__(16) __bf16 Bs[2][256 * 64];
  const int tid = threadIdx.x;
  const int wave = tid >> 6, lane = tid & 63;
  const int wm = wave >> 2, wn = wave & 3;      // 2 x 4 wave grid, wave tile 128x64
  const int rA = lane & 15, rG = lane >> 4;

  // XCD-aware bijective swizzle (nwg % 8 == 0 for all our grids)
  const int nwg = gridDim.x;
  const int cpx = nwg >> 3;
  const int wg = (blockIdx.x & 7) * cpx + (blockIdx.x >> 3);

  const int nbn = pr.N >> 8;
  const int bm = wg / nbn, bn = wg - bm * nbn;
  const int m0 = bm << 8, n0 = bn << 8;
  const int K = pr.K;
  const int NT = K >> 6;

  // staging geometry (shared by all 4 passes): 512 threads x 16B x 4 passes = 32KB/tile
  const int srow = wave * 8 + (lane >> 3);      // + r*64
  const int sslot = lane & 7;

  f32x4 acc[8][4] = {};

  // prologue: stage tile 0 into buf 0
#pragma unroll
  for (int r = 0; r < 4; ++r) {
    const int row = r * 64 + srow;
    const int fb = r * 8192 + wave * 1024;
    const int col = (sslot ^ (row & 7)) << 3;
    gld16(pr.A  + (size_t)(m0 + row) * K + col, (char*)As[0] + fb);
    gld16(pr.Bt + (size_t)(n0 + row) * K + col, (char*)Bs[0] + fb);
  }
  __syncthreads();

  int buf = 0;
  for (int t = 0; t < NT; ++t) {
    // prefetch next K-tile into the other buffer (issue BEFORE compute)
    if (t + 1 < NT) {
      const int k0 = (t + 1) << 6;
#pragma unroll
      for (int r = 0; r < 4; ++r) {
        const int row = r * 64 + srow;
        const int fb = r * 8192 + wave * 1024;
        const int col = k0 + ((sslot ^ (row & 7)) << 3);
        gld16(pr.A  + (size_t)(m0 + row) * K + col, (char*)As[buf ^ 1] + fb);
        gld16(pr.Bt + (size_t)(n0 + row) * K + col, (char*)Bs[buf ^ 1] + fb);
      }
    }
    // compute current buffer
#pragma unroll
    for (int kk = 0; kk < 2; ++kk) {
      bf16x8 af[8], bfv[4];
#pragma unroll
      for (int mt = 0; mt < 8; ++mt) {
        const int row = wm * 128 + mt * 16 + rA;
        const int slot = ((kk * 4 + rG) ^ (row & 7)) << 4;
        af[mt] = *(const bf16x8*)((const char*)As[buf] + row * 128 + slot);
      }
#pragma unroll
      for (int nt = 0; nt < 4; ++nt) {
        const int row = wn * 64 + nt * 16 + rA;
        const int slot = ((kk * 4 + rG) ^ (row & 7)) << 4;
        bfv[nt] = *(const bf16x8*)((const char*)Bs[buf] + row * 128 + slot);
      }
#pragma unroll
      for (int mt = 0; mt < 8; ++mt)
#pragma unroll
        for (int nt = 0; nt < 4; ++nt)
          acc[mt][nt] = __builtin_amdgcn_mfma_f32_16x16x32_bf16(bfv[nt], af[mt], acc[mt][nt], 0, 0, 0);
    }
    __syncthreads();   // waits vmcnt(0): prefetch landed; all reads of buf done
    buf ^= 1;
  }

  // epilogue: acc = C^T frag; lane owns row gr = m..+rA, cols d0..d0+3 (n-dim)
#pragma unroll
  for (int mt = 0; mt < 8; ++mt) {
    const int gr = m0 + wm * 128 + mt * 16 + rA;   // M index (b*2048+s)
    if constexpr (MODE == 0) {
      const int seg = n0 >> 10;
      const int dbase = n0 & 1023;
      __bf16* dst = (seg == 0) ? pr.qb : (seg == 1) ? pr.kb : (seg == 2) ? pr.vb : pr.ctxb;
      const bool isCtx = (seg == 3);
      const float dlv = isCtx ? pr.dl[gr] : 0.f;
      const int bkt = isCtx ? pr.bucket[gr] : 0;
      __bf16* rowp = dst + (size_t)gr * 1024;
#pragma unroll
      for (int nt = 0; nt < 4; ++nt) {
        const int d0 = dbase + wn * 64 + nt * 16 + rG * 4;
        bf16x4 o;
#pragma unroll
        for (int i = 0; i < 4; ++i) {
          const int d = d0 + i;
          float v = acc[mt][nt][i];
          if (isCtx) v += pr.biasp[d] + dlv * pr.wc_t[d] + pr.ebt[bkt * 1024 + d];
          else       v += pr.ebias[seg * 1024 + d];
          o[i] = (__bf16)v;
        }
        *(bf16x4*)(rowp + d0) = o;
      }
    } else {  // MODE == 2: f32 out + bo
      float* rowp = pr.outp + (size_t)gr * 1024;
#pragma unroll
      for (int nt = 0; nt < 4; ++nt) {
        const int d0 = n0 + wn * 64 + nt * 16 + rG * 4;
        f32x4 o;
#pragma unroll
        for (int i = 0; i < 4; ++i) o[i] = acc[mt][nt][i] + pr.bo[d0 + i];
        *(f32x4*)(rowp + d0) = o;
      }
    }
  }
}

// ---------------- GEMM 128x128 (m97 structure) kept for the small-N G2 ----------------

__global__ __launch_bounds__(256) void k_gemm1(GP pr) {
  __shared__ __bf16 As[128 * 32];
  __shared__ __bf16 Bs[128 * 32];
  const int tid = threadIdx.x;
  const int wave = tid >> 6, lane = tid & 63;
  const int wm = wave >> 1, wn = wave & 1;
  const int nbn = pr.N >> 7;
  const int bm = blockIdx.x / nbn, bn = blockIdx.x - bm * nbn;
  const int m0 = bm << 7, n0 = bn << 7;
  const int K = pr.K;
  const int rA = lane & 15, rG = lane >> 4;

  f32x4 acc[4][4] = {};

  for (int k0 = 0; k0 < K; k0 += 32) {
#pragma unroll
    for (int ch = 0; ch < 2; ++ch) {
      const int fb = ch * 4096 + wave * 1024;
      const int e = (fb >> 1) + lane * 8;
      const int row = e >> 5, col = e & 31;
      gld16(pr.A  + (size_t)(m0 + row) * K + (k0 + col), (char*)As + fb);
      gld16(pr.Bt + (size_t)(n0 + row) * K + (k0 + col), (char*)Bs + fb);
    }
    __syncthreads();

    bf16x8 af[4], bfv[4];
#pragma unroll
    for (int mt = 0; mt < 4; ++mt)
      af[mt] = *(const bf16x8*)&As[(wm * 64 + mt * 16 + rA) * 32 + rG * 8];
#pragma unroll
    for (int nt = 0; nt < 4; ++nt)
      bfv[nt] = *(const bf16x8*)&Bs[(wn * 64 + nt * 16 + rA) * 32 + rG * 8];
#pragma unroll
    for (int mt = 0; mt < 4; ++mt)
#pragma unroll
      for (int nt = 0; nt < 4; ++nt)
        acc[mt][nt] = __builtin_amdgcn_mfma_f32_16x16x32_bf16(af[mt], bfv[nt], acc[mt][nt], 0, 0, 0);
    __syncthreads();
  }

  // MODE 1 epilogue (C layout: col = lane&15, row = (lane>>4)*4 + i)
#pragma unroll
  for (int mt = 0; mt < 4; ++mt) {
#pragma unroll
    for (int nt = 0; nt < 4; ++nt) {
      const int gc = n0 + wn * 64 + nt * 16 + rA;
      const int grb = m0 + wm * 64 + mt * 16 + rG * 4;
#pragma unroll
      for (int i = 0; i < 4; ++i) {
        const int gr = grb + i;
        float val = acc[mt][nt][i];
        const int bb = gr >> 11, ss = gr & 2047;
        const int half = gc >> 7, j = gc & 127;
        const int hh = j >> 3, pp = j & 7;
        size_t di = (((size_t)bb * NH + hh) * S_LEN + ss) * NP + pp;
        if (half == 0) pr.offa[di] = tanhf(val + pr.boff[j]);
        else           pr.psa[di]  = val + pr.bps[j];
      }
    }
  }
}

// ---------------- deformable attention: one wave per (b,h,s); q/k/v in [B,S,D] ----------------

__global__ __launch_bounds__(256) void k_attn(
    const __bf16* __restrict__ qb, const __bf16* __restrict__ kb, const __bf16* __restrict__ vb,
    const float* __restrict__ offa, const float* __restrict__ psa,
    const float* __restrict__ elapsed,
    const float* __restrict__ point_bias, const float* __restrict__ tdw,
    const float* __restrict__ tdb,
    __bf16* __restrict__ attn_out) {
  const int wid = blockIdx.x * 4 + (threadIdx.x >> 6);
  const int lane = threadIdx.x & 63;
  const int s = wid & (S_LEN - 1);
  const int h = (wid >> 11) & (NH - 1);
  const int b = wid >> 15;
  const int p = lane >> 3, c = lane & 7;

  const double step = log2(129.0) / 7.0;
  const float anchor = (p == 0) ? 0.0f : (float)(exp2((double)p * step) - 1.0);

  const size_t bBase = (size_t)b * S_LEN;
  const size_t ppos = (((size_t)b * NH + h) * S_LEN + s) * NP + p;
  const float off = offa[ppos];
  const float psv = psa[ppos];

  float pos = (float)s - anchor + off * 8.0f;
  pos = fminf(fmaxf(pos, 0.0f), (float)s);
  int li = (int)pos; if (li > S_LEN - 1) li = S_LEN - 1;
  const float alpha = pos - (float)li;
  int ri = li + 1; if (ri > S_LEN - 1) ri = S_LEN - 1;

  const int hd = h * 64 + c * 8;
  const bf16x8 qv = *(const bf16x8*)(qb + (bBase + s) * DIM + hd);
  const bf16x8 kl = *(const bf16x8*)(kb + (bBase + li) * DIM + hd);
  const bf16x8 kr = *(const bf16x8*)(kb + (bBase + ri) * DIM + hd);

  float dot = 0.f;
#pragma unroll
  for (int j = 0; j < 8; ++j) {
    float klj = (float)kl[j];
    float kf = klj + alpha * ((float)kr[j] - klj);
    dot += (float)qv[j] * kf;
  }
  dot += __shfl_xor(dot, 1);
  dot += __shfl_xor(dot, 2);
  dot += __shfl_xor(dot, 4);

  const float el_s = elapsed[b * S_LEN + s];
  const float ell = elapsed[b * S_LEN + li];
  const float elr = elapsed[b * S_LEN + ri];
  const float elsamp = ell + alpha * (elr - ell);
  const float rel = log1pf(fmaxf(el_s - elsamp, 0.f));
  const int hp = h * NP + p;
  const float decay = log1pf(expf(tdw[hp]));
  float score = dot * 0.125f + psv + tdb[hp] - decay * rel + point_bias[hp];

  float m = score;
  m = fmaxf(m, __shfl_xor(m, 8));
  m = fmaxf(m, __shfl_xor(m, 16));
  m = fmaxf(m, __shfl_xor(m, 32));
  float e = expf(score - m);
  float dsum = e;
  dsum += __shfl_xor(dsum, 8);
  dsum += __shfl_xor(dsum, 16);
  dsum += __shfl_xor(dsum, 32);
  const float w = e / dsum;

  const bf16x8 vl = *(const bf16x8*)(vb + (bBase + li) * DIM + hd);
  const bf16x8 vr = *(const bf16x8*)(vb + (bBase + ri) * DIM + hd);
  float o[8];
#pragma unroll
  for (int j = 0; j < 8; ++j) {
    float vlj = (float)vl[j];
    float vf = vlj + alpha * ((float)vr[j] - vlj);
    o[j] = w * vf;
  }
#pragma unroll
  for (int j = 0; j < 8; ++j) {
    o[j] += __shfl_xor(o[j], 8);
    o[j] += __shfl_xor(o[j], 16);
    o[j] += __shfl_xor(o[j], 32);
  }
  if (p == 0) {
    bf16x8 ov;
#pragma unroll
    for (int j = 0; j < 8; ++j) ov[j] = (__bf16)o[j];
    *(bf16x8*)(attn_out + ((size_t)b * S_LEN + s) * DIM + h * 64 + c * 8) = ov;
  }
}

// ---------------- host ----------------

extern "C" void kernel_launch(void* const* d_in, const int* in_sizes, int n_in,
                              void* d_out, int out_size, void* d_ws, size_t ws_size,
                              hipStream_t stream) {
  const float* x    = (const float*)d_in[0];
  const float* td   = (const float*)d_in[1];
  const float* Wq   = (const float*)d_in[2];
  const float* bq   = (const float*)d_in[3];
  const float* Wk   = (const float*)d_in[4];
  const float* bk   = (const float*)d_in[5];
  const float* Wv   = (const float*)d_in[6];
  const float* bv   = (const float*)d_in[7];
  const float* Wc   = (const float*)d_in[8];
  const float* bc   = (const float*)d_in[9];
  const float* Eb   = (const float*)d_in[10];
  const float* Wt   = (const float*)d_in[11];
  const float* bt   = (const float*)d_in[12];
  const float* Woff = (const float*)d_in[13];
  const float* boff = (const float*)d_in[14];
  const float* Wps  = (const float*)d_in[15];
  const float* bps  = (const float*)d_in[16];
  const float* Wo   = (const float*)d_in[17];
  const float* bo   = (const float*)d_in[18];
  const float* pb   = (const float*)d_in[19];
  const float* tdw  = (const float*)d_in[20];
  const float* tdb  = (const float*)d_in[21];

  char* w = (char*)d_ws;
  size_t off = 0;
  auto take = [&](size_t n) {
    char* pp = w + off;
    off += (n + 255) & ~(size_t)255;
    return pp;
  };
  __bf16* xb    = (__bf16*)take(33554432);  // x bf16 [16384,1024]; reused as attn_out
  __bf16* wcat  = (__bf16*)take(8388608);   // [4096,1024] B^T of Wq|Wk|Wv|Wt1
  __bf16* w2t   = (__bf16*)take(524288);    // [256,1024] B^T of Woff|Wps
  __bf16* wot   = (__bf16*)take(2097152);   // [1024,1024] B^T of Wo
  __bf16* qb    = (__bf16*)take(33554432);  // [B,S,D]
  __bf16* kb    = (__bf16*)take(33554432);
  __bf16* vb    = (__bf16*)take(33554432);
  __bf16* ctxb  = (__bf16*)take(33554432);  // [16384,1024]
  float* offa   = (float*)take(8388608);    // [B,H,S,P]
  float* psa    = (float*)take(8388608);
  float* elap   = (float*)take(65536);
  float* dl     = (float*)take(65536);
  int*   bucket = (int*)take(65536);
  float* wc_t   = (float*)take(4096);
  float* ebt    = (float*)take(36864);
  float* biasp  = (float*)take(4096);
  float* ebias  = (float*)take(12288);
  if (off > ws_size) return;
  __bf16* attn_out = xb;  // alias: xb dead after G1

  k_cast_bf16<<<16384, 256, 0, stream>>>(x, xb, 4194304);
  k_pack_wt2<<<256, 256, 0, stream>>>(Wq, wcat, 1024, 1024);
  k_pack_wt2<<<256, 256, 0, stream>>>(Wk, wcat + 1048576, 1024, 1024);
  k_pack_wt2<<<256, 256, 0, stream>>>(Wv, wcat + 2097152, 1024, 1024);
  k_pack_wt2<<<256, 256, 0, stream>>>(Wt, wcat + 3145728, 1024, 1024);
  k_pack_wt2<<<32, 256, 0, stream>>>(Woff, w2t, 1024, 128);
  k_pack_wt2<<<32, 256, 0, stream>>>(Wps, w2t + 131072, 1024, 128);
  k_pack_wt2<<<256, 256, 0, stream>>>(Wo, wot, 1024, 1024);
  k_ebias<<<12, 256, 0, stream>>>(bq, bk, bv, ebias);
  k_precompute<<<4, 256, 0, stream>>>(Wc, bc, Eb, Wt, bt, wc_t, ebt, biasp);
  k_rowfeat<<<64, 256, 0, stream>>>(td, dl, bucket, 16384);
  k_cumsum<<<8, 256, 0, stream>>>(td, elap);

  GP g1 = {};
  g1.A = xb; g1.Bt = wcat; g1.M = 16384; g1.N = 4096; g1.K = 1024;
  g1.qb = qb; g1.kb = kb; g1.vb = vb; g1.ctxb = ctxb;
  g1.ebias = ebias; g1.biasp = biasp; g1.wc_t = wc_t; g1.ebt = ebt;
  g1.dl = dl; g1.bucket = bucket;
  k_gemm2<0><<<64 * 16, 512, 0, stream>>>(g1);

  GP g2 = {};
  g2.A = ctxb; g2.Bt = w2t; g2.M = 16384; g2.N = 256; g2.K = 1024;
  g2.offa = offa; g2.psa = psa; g2.boff = boff; g2.bps = bps;
  k_gemm1<<<128 * 2, 256, 0, stream>>>(g2);

  k_attn<<<65536, 256, 0, stream>>>(qb, kb, vb, offa, psa, elap, pb, tdw, tdb, attn_out);

  GP g3 = {};
  g3.A = attn_out; g3.Bt = wot; g3.M = 16384; g3.N = 1024; g3.K = 1024;
  g3.outp = (float*)d_out; g3.bo = bo;
  k_gemm2<2><<<64 * 4, 512, 0, stream>>>(g3);
}